// Round 1
// baseline (12160.979 us; speedup 1.0000x reference)
//
#include <hip/hip_runtime.h>

// LightGCN forward: acc = sum over layers of (A^l @ X), A sparse COO (src,dst,w).
// Layout: d_out = acc (n_nodes x 64 f32). d_ws = two ping-pong embedding buffers.

#define D 64

// cur = ini; acc = ini; nxt = 0   (one fused pass, float4)
__global__ void lg_init_kernel(const float* __restrict__ ini,
                               float* __restrict__ cur,
                               float* __restrict__ acc,
                               float* __restrict__ nxt, int n4) {
    int i = blockIdx.x * blockDim.x + threadIdx.x;
    int stride = gridDim.x * blockDim.x;
    const float4* s = (const float4*)ini;
    float4* c = (float4*)cur;
    float4* a = (float4*)acc;
    float4* z = (float4*)nxt;
    float4 zero = make_float4(0.f, 0.f, 0.f, 0.f);
    for (; i < n4; i += stride) {
        float4 v = s[i];
        c[i] = v;
        a[i] = v;
        z[i] = zero;
    }
}

// y[dst] += w * x[src]  — 16 lanes per edge, one float4 gather + 4 fp32 HW atomics per lane
__global__ void lg_spmm_kernel(const int* __restrict__ esrc,
                               const int* __restrict__ edst,
                               const float* __restrict__ ew,
                               const float* __restrict__ x,
                               float* __restrict__ y, int E) {
    int tid = blockIdx.x * blockDim.x + threadIdx.x;
    int e = tid >> 4;
    if (e >= E) return;
    int l = (tid & 15) << 2;           // float offset within row: 0,4,...,60
    int s = esrc[e];
    int d = edst[e];
    float w = ew[e];
    float4 v = *(const float4*)(x + s * D + l);
    float* yp = y + d * D + l;
    unsafeAtomicAdd(yp + 0, w * v.x);
    unsafeAtomicAdd(yp + 1, w * v.y);
    unsafeAtomicAdd(yp + 2, w * v.z);
    unsafeAtomicAdd(yp + 3, w * v.w);
}

// acc += nxt; zbuf = 0   (fused pass; zbuf is the just-consumed layer buffer)
__global__ void lg_addzero_kernel(float* __restrict__ acc,
                                  const float* __restrict__ nxt,
                                  float* __restrict__ zbuf, int n4) {
    int i = blockIdx.x * blockDim.x + threadIdx.x;
    int stride = gridDim.x * blockDim.x;
    float4* a = (float4*)acc;
    const float4* n = (const float4*)nxt;
    float4* z = (float4*)zbuf;
    float4 zero = make_float4(0.f, 0.f, 0.f, 0.f);
    for (; i < n4; i += stride) {
        float4 av = a[i];
        float4 nv = n[i];
        av.x += nv.x; av.y += nv.y; av.z += nv.z; av.w += nv.w;
        a[i] = av;
        z[i] = zero;
    }
}

extern "C" void kernel_launch(void* const* d_in, const int* in_sizes, int n_in,
                              void* d_out, int out_size, void* d_ws, size_t ws_size,
                              hipStream_t stream) {
    const float* ini  = (const float*)d_in[0];
    const int*   esrc = (const int*)d_in[1];
    const int*   edst = (const int*)d_in[2];
    const float* ew   = (const float*)d_in[3];
    // d_in[4] = n_user, d_in[5] = n_layers (device scalars; n_layers fixed at 3 per reference)

    int n_nodes = in_sizes[0] / D;     // 150000
    int E       = in_sizes[1];         // 4.8M
    int n4      = (n_nodes * D) / 4;   // float4 count = 2.4M

    float* acc = (float*)d_out;
    float* cur = (float*)d_ws;
    float* nxt = cur + (size_t)n_nodes * D;

    lg_init_kernel<<<2048, 256, 0, stream>>>(ini, cur, acc, nxt, n4);

    int spmm_threads = E * 16;                       // 76.8M, fits int32
    int spmm_blocks  = (spmm_threads + 255) / 256;

    for (int layer = 0; layer < 3; ++layer) {
        lg_spmm_kernel<<<spmm_blocks, 256, 0, stream>>>(esrc, edst, ew, cur, nxt, E);
        lg_addzero_kernel<<<2048, 256, 0, stream>>>(acc, nxt, cur, n4);
        float* t = cur; cur = nxt; nxt = t;
    }
}

// Round 2
// 1712.454 us; speedup vs baseline: 7.1015x; 7.1015x over previous
//
#include <hip/hip_runtime.h>

// LightGCN forward: acc = sum over layers of (A^l @ X), A sparse COO (src,dst,w).
// Strategy: build dst-CSR once per launch (hist + scan + scatter into d_ws),
// then each layer is an atomic-free gather SpMM (1 wave per dst node,
// lane = feature dim), fused with the running layer-sum into d_out.

#define D 64

// ---------------- CSR build ----------------

__global__ void lg_zero_int(int* __restrict__ p, int n) {
    int i = blockIdx.x * blockDim.x + threadIdx.x;
    int st = gridDim.x * blockDim.x;
    for (; i < n; i += st) p[i] = 0;
}

__global__ void lg_hist(const int* __restrict__ edst, int* __restrict__ counts, int E) {
    int i = blockIdx.x * blockDim.x + threadIdx.x;
    int st = gridDim.x * blockDim.x;
    for (; i < E; i += st) atomicAdd(&counts[edst[i]], 1);
}

// Single-block exclusive scan over counts[n] -> rowptr[n+1], cursor[n].
// n = 150000: each of 1024 threads serially scans ~147 elements, then a
// Hillis-Steele scan over the 1024 per-thread sums. Runs once per launch.
__global__ __launch_bounds__(1024) void lg_scan(const int* __restrict__ counts,
                                                int* __restrict__ rowptr,
                                                int* __restrict__ cursor,
                                                int n, int E) {
    __shared__ int lds[1024];
    int tid = threadIdx.x;
    int per = (n + 1023) >> 10;
    int lo = tid * per; if (lo > n) lo = n;
    int hi = lo + per;  if (hi > n) hi = n;
    int sum = 0;
    for (int i = lo; i < hi; ++i) sum += counts[i];
    lds[tid] = sum;
    __syncthreads();
    for (int off = 1; off < 1024; off <<= 1) {
        int v = (tid >= off) ? lds[tid - off] : 0;
        __syncthreads();
        lds[tid] += v;
        __syncthreads();
    }
    int run = lds[tid] - sum;  // exclusive prefix of this thread's chunk
    for (int i = lo; i < hi; ++i) {
        rowptr[i] = run;
        cursor[i] = run;
        run += counts[i];
    }
    if (tid == 0) rowptr[n] = E;
}

__global__ void lg_scatter(const int* __restrict__ esrc, const int* __restrict__ edst,
                           const float* __restrict__ ew, int* __restrict__ cursor,
                           int2* __restrict__ edata, int E) {
    int i = blockIdx.x * blockDim.x + threadIdx.x;
    int st = gridDim.x * blockDim.x;
    for (; i < E; i += st) {
        int p = atomicAdd(&cursor[edst[i]], 1);
        edata[p] = make_int2(esrc[i], __float_as_int(ew[i]));
    }
}

// ---------------- gather SpMM (atomic-free) ----------------
// One 64-lane wave per dst node; lane = feature dim. Edge (src,w) pairs are
// loaded 64-at-a-time coalesced, then shfl-broadcast to all lanes.
template <bool FIRST>
__global__ void lg_gather(const int2* __restrict__ edata, const int* __restrict__ rowptr,
                          const float* __restrict__ x, float* __restrict__ y,
                          float* __restrict__ acc, const float* __restrict__ ini,
                          int n_nodes) {
    int wid = (blockIdx.x * blockDim.x + threadIdx.x) >> 6;
    int lane = threadIdx.x & 63;
    if (wid >= n_nodes) return;
    int start = rowptr[wid];
    int end = rowptr[wid + 1];
    float accv = 0.f;
    for (int base = start; base < end; base += 64) {
        int n = end - base; if (n > 64) n = 64;
        int s = 0; float w = 0.f;
        if (lane < n) {
            int2 ed = edata[base + lane];
            s = ed.x;
            w = __int_as_float(ed.y);
        }
        for (int j = 0; j < n; ++j) {
            int ss = __shfl(s, j);
            float wf = __shfl(w, j);
            accv += wf * x[(size_t)ss * D + lane];
        }
    }
    size_t o = (size_t)wid * D + lane;
    y[o] = accv;
    if (FIRST) acc[o] = ini[o] + accv;
    else       acc[o] += accv;
}

// ---------------- fallback (round-1 atomic path) ----------------

__global__ void lg_init_kernel(const float* __restrict__ ini, float* __restrict__ cur,
                               float* __restrict__ acc, float* __restrict__ nxt, int n4) {
    int i = blockIdx.x * blockDim.x + threadIdx.x;
    int stride = gridDim.x * blockDim.x;
    const float4* s = (const float4*)ini;
    float4* c = (float4*)cur; float4* a = (float4*)acc; float4* z = (float4*)nxt;
    float4 zero = make_float4(0.f, 0.f, 0.f, 0.f);
    for (; i < n4; i += stride) { float4 v = s[i]; c[i] = v; a[i] = v; z[i] = zero; }
}

__global__ void lg_spmm_kernel(const int* __restrict__ esrc, const int* __restrict__ edst,
                               const float* __restrict__ ew, const float* __restrict__ x,
                               float* __restrict__ y, int E) {
    int tid = blockIdx.x * blockDim.x + threadIdx.x;
    int e = tid >> 4;
    if (e >= E) return;
    int l = (tid & 15) << 2;
    int s = esrc[e]; int d = edst[e]; float w = ew[e];
    float4 v = *(const float4*)(x + s * D + l);
    float* yp = y + d * D + l;
    unsafeAtomicAdd(yp + 0, w * v.x);
    unsafeAtomicAdd(yp + 1, w * v.y);
    unsafeAtomicAdd(yp + 2, w * v.z);
    unsafeAtomicAdd(yp + 3, w * v.w);
}

__global__ void lg_addzero_kernel(float* __restrict__ acc, const float* __restrict__ nxt,
                                  float* __restrict__ zbuf, int n4) {
    int i = blockIdx.x * blockDim.x + threadIdx.x;
    int stride = gridDim.x * blockDim.x;
    float4* a = (float4*)acc; const float4* n = (const float4*)nxt; float4* z = (float4*)zbuf;
    float4 zero = make_float4(0.f, 0.f, 0.f, 0.f);
    for (; i < n4; i += stride) {
        float4 av = a[i]; float4 nv = n[i];
        av.x += nv.x; av.y += nv.y; av.z += nv.z; av.w += nv.w;
        a[i] = av; z[i] = zero;
    }
}

extern "C" void kernel_launch(void* const* d_in, const int* in_sizes, int n_in,
                              void* d_out, int out_size, void* d_ws, size_t ws_size,
                              hipStream_t stream) {
    const float* ini  = (const float*)d_in[0];
    const int*   esrc = (const int*)d_in[1];
    const int*   edst = (const int*)d_in[2];
    const float* ew   = (const float*)d_in[3];

    int n_nodes = in_sizes[0] / D;     // 150000
    int E       = in_sizes[1];         // 4.8M

    size_t embBytes = (size_t)n_nodes * D * sizeof(float);     // 38.4 MB
    size_t edataBytes = (size_t)E * sizeof(int2);              // 38.4 MB
    size_t need = 2 * embBytes + edataBytes + ((size_t)n_nodes + 1) * 4 + (size_t)n_nodes * 4 + 64;

    float* acc = (float*)d_out;

    if (ws_size >= need) {
        // ---- CSR gather path ----
        char* p = (char*)d_ws;
        float* buf0  = (float*)p;                 p += embBytes;
        float* buf1  = (float*)p;                 p += embBytes;
        int2*  edata = (int2*)p;                  p += edataBytes;
        int*   rowptr = (int*)p;                  p += ((size_t)n_nodes + 1) * 4;
        // align cursor to 16
        p = (char*)(((uintptr_t)p + 15) & ~(uintptr_t)15);
        int*   cursor = (int*)p;

        lg_zero_int<<<(n_nodes + 255) / 256, 256, 0, stream>>>(cursor, n_nodes);
        lg_hist<<<2048, 256, 0, stream>>>(edst, cursor, E);
        lg_scan<<<1, 1024, 0, stream>>>(cursor, rowptr, cursor, n_nodes, E);
        // NOTE: scan reads counts from cursor and rewrites cursor with row starts
        lg_scatter<<<2048, 256, 0, stream>>>(esrc, edst, ew, cursor, edata, E);

        int gblocks = (n_nodes * 64 + 255) / 256;  // 1 wave per node, 4 waves/block
        lg_gather<true ><<<gblocks, 256, 0, stream>>>(edata, rowptr, ini,  buf0, acc, ini, n_nodes);
        lg_gather<false><<<gblocks, 256, 0, stream>>>(edata, rowptr, buf0, buf1, acc, ini, n_nodes);
        lg_gather<false><<<gblocks, 256, 0, stream>>>(edata, rowptr, buf1, buf0, acc, ini, n_nodes);
    } else {
        // ---- fallback: atomic scatter path ----
        int n4 = (n_nodes * D) / 4;
        float* cur = (float*)d_ws;
        float* nxt = cur + (size_t)n_nodes * D;
        lg_init_kernel<<<2048, 256, 0, stream>>>(ini, cur, acc, nxt, n4);
        int spmm_blocks = (E * 16 + 255) / 256;
        for (int layer = 0; layer < 3; ++layer) {
            lg_spmm_kernel<<<spmm_blocks, 256, 0, stream>>>(esrc, edst, ew, cur, nxt, E);
            lg_addzero_kernel<<<2048, 256, 0, stream>>>(acc, nxt, cur, n4);
            float* t = cur; cur = nxt; nxt = t;
        }
    }
}

// Round 3
// 1091.240 us; speedup vs baseline: 11.1442x; 1.5693x over previous
//
#include <hip/hip_runtime.h>

// LightGCN forward: acc = sum over layers of (A^l @ X), A sparse COO (src,dst,w).
// Build dst-sorted CSR once per launch via two-phase counting sort
// (bucket = dst>>6, cache-local scatter windows), then 3 atomic-free gather
// SpMM layers (wave per dst node, quarter-wave per edge, float4 lanes).

#define D 64
#define BSH 6
#define BWIDTH 64   // nodes per bucket = 1<<BSH

__global__ void lg_zero_int(int* __restrict__ p, int n) {
    int i = blockIdx.x * blockDim.x + threadIdx.x;
    int st = gridDim.x * blockDim.x;
    for (; i < n; i += st) p[i] = 0;
}

// bucket histogram, LDS-aggregated (low global-atomic contention)
__global__ void lg_bhist(const int* __restrict__ edst, int* __restrict__ bcount,
                         int E, int NB) {
    extern __shared__ int lcnt[];
    for (int i = threadIdx.x; i < NB; i += blockDim.x) lcnt[i] = 0;
    __syncthreads();
    int i = blockIdx.x * blockDim.x + threadIdx.x;
    int st = gridDim.x * blockDim.x;
    for (; i < E; i += st) atomicAdd(&lcnt[edst[i] >> BSH], 1);
    __syncthreads();
    for (int j = threadIdx.x; j < NB; j += blockDim.x) {
        int v = lcnt[j];
        if (v) atomicAdd(&bcount[j], v);
    }
}

// single-block scan over NB bucket counts; counts may alias bcur (pre-loaded).
__global__ __launch_bounds__(1024) void lg_bscan(const int* counts, int* bptr, int* bcur,
                                                 int NB, int E, int* rowptr, int n_nodes) {
    __shared__ int lds[1024];
    int tid = threadIdx.x;
    int per = (NB + 1023) >> 10;
    int lo = tid * per; if (lo > NB) lo = NB;
    int hi = lo + per;  if (hi > NB) hi = NB;
    int sum = 0;
    for (int i = lo; i < hi; ++i) sum += counts[i];
    lds[tid] = sum;
    __syncthreads();
    for (int off = 1; off < 1024; off <<= 1) {
        int v = (tid >= off) ? lds[tid - off] : 0;
        __syncthreads();
        lds[tid] += v;
        __syncthreads();
    }
    int run = lds[tid] - sum;
    for (int i = lo; i < hi; ++i) {
        int c = counts[i];          // load BEFORE overwriting (counts==bcur)
        bptr[i] = run;
        bcur[i] = run;
        run += c;
    }
    if (tid == 0) { bptr[NB] = E; rowptr[n_nodes] = E; }
}

// phase 1: edges -> bucket order. record {src | (dst&63)<<18, w_bits}
__global__ void lg_bscatter(const int* __restrict__ esrc, const int* __restrict__ edst,
                            const float* __restrict__ ew, int* __restrict__ bcur,
                            int2* __restrict__ bbuf, int E) {
    int i = blockIdx.x * blockDim.x + threadIdx.x;
    int st = gridDim.x * blockDim.x;
    for (; i < E; i += st) {
        int d = edst[i];
        int p = atomicAdd(&bcur[d >> BSH], 1);
        bbuf[p] = make_int2(esrc[i] | ((d & (BWIDTH - 1)) << 18), __float_as_int(ew[i]));
    }
}

// phase 2: per-bucket LDS counting sort -> dst-sorted edata + rowptr
__global__ __launch_bounds__(256) void lg_bfinal(const int2* __restrict__ bbuf,
                                                 const int* __restrict__ bptr,
                                                 int2* __restrict__ edata,
                                                 int* __restrict__ rowptr, int n_nodes) {
    __shared__ int cnt[BWIDTH];
    __shared__ int cur[BWIDTH];
    int b = blockIdx.x;
    int s = bptr[b], e = bptr[b + 1];
    int tid = threadIdx.x;
    if (tid < BWIDTH) cnt[tid] = 0;
    __syncthreads();
    for (int i = s + tid; i < e; i += 256)
        atomicAdd(&cnt[(unsigned)bbuf[i].x >> 18], 1);
    __syncthreads();
    if (tid < BWIDTH) {  // exactly wave 0: prefix scan over 64 node counts
        int v = cnt[tid];
        int incl = v;
        for (int off = 1; off < BWIDTH; off <<= 1) {
            int t = __shfl_up(incl, off);
            if (tid >= off) incl += t;
        }
        int excl = incl - v;
        cur[tid] = excl;
        int node = b * BWIDTH + tid;
        if (node < n_nodes) rowptr[node] = s + excl;
    }
    __syncthreads();
    for (int i = s + tid; i < e; i += 256) {
        int2 ed = bbuf[i];
        int loc = (unsigned)ed.x >> 18;
        int p = s + atomicAdd(&cur[loc], 1);
        edata[p] = make_int2(ed.x & 0x3FFFF, ed.y);
    }
}

// gather SpMM: wave per dst node, quarter-wave per edge, float4 lanes, 2-deep unroll
template <bool FIRST>
__global__ __launch_bounds__(256) void lg_gather(const int2* __restrict__ edata,
                                                 const int* __restrict__ rowptr,
                                                 const float* __restrict__ x,
                                                 float* __restrict__ y,
                                                 float* __restrict__ acc,
                                                 const float* __restrict__ ini,
                                                 int n_nodes) {
    int wid = (blockIdx.x * blockDim.x + threadIdx.x) >> 6;
    int lane = threadIdx.x & 63;
    if (wid >= n_nodes) return;
    int q = lane >> 4, c = lane & 15;
    int start = rowptr[wid], end = rowptr[wid + 1];
    float ax = 0.f, ay = 0.f, az = 0.f, aw = 0.f;
    int base = start;
    for (; base + 8 <= end; base += 8) {
        int2 e0 = edata[base + q];
        int2 e1 = edata[base + 4 + q];
        float w0 = __int_as_float(e0.y);
        float w1 = __int_as_float(e1.y);
        float4 x0 = *((const float4*)(x + (size_t)e0.x * D) + c);
        float4 x1 = *((const float4*)(x + (size_t)e1.x * D) + c);
        ax += w0 * x0.x; ay += w0 * x0.y; az += w0 * x0.z; aw += w0 * x0.w;
        ax += w1 * x1.x; ay += w1 * x1.y; az += w1 * x1.z; aw += w1 * x1.w;
    }
    for (; base < end; base += 4) {
        int idx = base + q;
        if (idx < end) {
            int2 e0 = edata[idx];
            float w0 = __int_as_float(e0.y);
            float4 x0 = *((const float4*)(x + (size_t)e0.x * D) + c);
            ax += w0 * x0.x; ay += w0 * x0.y; az += w0 * x0.z; aw += w0 * x0.w;
        }
    }
    ax += __shfl_xor(ax, 16); ax += __shfl_xor(ax, 32);
    ay += __shfl_xor(ay, 16); ay += __shfl_xor(ay, 32);
    az += __shfl_xor(az, 16); az += __shfl_xor(az, 32);
    aw += __shfl_xor(aw, 16); aw += __shfl_xor(aw, 32);
    if (lane < 16) {
        size_t o = (size_t)wid * D + (size_t)c * 4;
        *(float4*)(y + o) = make_float4(ax, ay, az, aw);
        if (FIRST) {
            float4 iv = *(const float4*)(ini + o);
            *(float4*)(acc + o) = make_float4(iv.x + ax, iv.y + ay, iv.z + az, iv.w + aw);
        } else {
            float4 av = *(float4*)(acc + o);
            *(float4*)(acc + o) = make_float4(av.x + ax, av.y + ay, av.z + az, av.w + aw);
        }
    }
}

// fallback (atomic scatter path, only if ws too small)
__global__ void lg_init_kernel(const float* __restrict__ ini, float* __restrict__ cur,
                               float* __restrict__ acc, float* __restrict__ nxt, int n4) {
    int i = blockIdx.x * blockDim.x + threadIdx.x;
    int stride = gridDim.x * blockDim.x;
    const float4* s = (const float4*)ini;
    float4* c = (float4*)cur; float4* a = (float4*)acc; float4* z = (float4*)nxt;
    float4 zero = make_float4(0.f, 0.f, 0.f, 0.f);
    for (; i < n4; i += stride) { float4 v = s[i]; c[i] = v; a[i] = v; z[i] = zero; }
}

__global__ void lg_spmm_kernel(const int* __restrict__ esrc, const int* __restrict__ edst,
                               const float* __restrict__ ew, const float* __restrict__ x,
                               float* __restrict__ y, int E) {
    int tid = blockIdx.x * blockDim.x + threadIdx.x;
    int e = tid >> 4;
    if (e >= E) return;
    int l = (tid & 15) << 2;
    int s = esrc[e]; int d = edst[e]; float w = ew[e];
    float4 v = *(const float4*)(x + s * D + l);
    float* yp = y + d * D + l;
    unsafeAtomicAdd(yp + 0, w * v.x);
    unsafeAtomicAdd(yp + 1, w * v.y);
    unsafeAtomicAdd(yp + 2, w * v.z);
    unsafeAtomicAdd(yp + 3, w * v.w);
}

__global__ void lg_addzero_kernel(float* __restrict__ acc, const float* __restrict__ nxt,
                                  float* __restrict__ zbuf, int n4) {
    int i = blockIdx.x * blockDim.x + threadIdx.x;
    int stride = gridDim.x * blockDim.x;
    float4* a = (float4*)acc; const float4* n = (const float4*)nxt; float4* z = (float4*)zbuf;
    float4 zero = make_float4(0.f, 0.f, 0.f, 0.f);
    for (; i < n4; i += stride) {
        float4 av = a[i]; float4 nv = n[i];
        av.x += nv.x; av.y += nv.y; av.z += nv.z; av.w += nv.w;
        a[i] = av; z[i] = zero;
    }
}

extern "C" void kernel_launch(void* const* d_in, const int* in_sizes, int n_in,
                              void* d_out, int out_size, void* d_ws, size_t ws_size,
                              hipStream_t stream) {
    const float* ini  = (const float*)d_in[0];
    const int*   esrc = (const int*)d_in[1];
    const int*   edst = (const int*)d_in[2];
    const float* ew   = (const float*)d_in[3];

    int n_nodes = in_sizes[0] / D;     // 150000
    int E       = in_sizes[1];         // 4.8M
    int NB      = (n_nodes + BWIDTH - 1) >> BSH;

    size_t embBytes   = (size_t)n_nodes * D * sizeof(float);   // 38.4 MB
    size_t edataBytes = (size_t)E * sizeof(int2);              // 38.4 MB
    size_t ptrBytes   = (((size_t)n_nodes + 1) * 4 + 15) & ~(size_t)15;
    size_t bptrBytes  = (((size_t)NB + 1) * 4 + 15) & ~(size_t)15;
    size_t need = 2 * embBytes + edataBytes + ptrBytes + bptrBytes + (size_t)NB * 4 + 64;

    float* acc = (float*)d_out;

    if (ws_size >= need) {
        char* p = (char*)d_ws;
        float* buf0   = (float*)p;  p += embBytes;
        float* buf1   = (float*)p;  p += embBytes;   // doubles as bbuf during build
        int2*  edata  = (int2*)p;   p += edataBytes;
        int*   rowptr = (int*)p;    p += ptrBytes;
        int*   bptr   = (int*)p;    p += bptrBytes;
        int*   bcur   = (int*)p;
        int2*  bbuf   = (int2*)buf1;

        lg_zero_int<<<(NB + 255) / 256, 256, 0, stream>>>(bcur, NB);
        lg_bhist<<<256, 256, (size_t)NB * 4, stream>>>(edst, bcur, E, NB);
        lg_bscan<<<1, 1024, 0, stream>>>(bcur, bptr, bcur, NB, E, rowptr, n_nodes);
        lg_bscatter<<<2048, 256, 0, stream>>>(esrc, edst, ew, bcur, bbuf, E);
        lg_bfinal<<<NB, 256, 0, stream>>>(bbuf, bptr, edata, rowptr, n_nodes);

        int gblocks = (int)(((size_t)n_nodes * 64 + 255) / 256);
        lg_gather<true ><<<gblocks, 256, 0, stream>>>(edata, rowptr, ini,  buf0, acc, ini, n_nodes);
        lg_gather<false><<<gblocks, 256, 0, stream>>>(edata, rowptr, buf0, buf1, acc, ini, n_nodes);
        lg_gather<false><<<gblocks, 256, 0, stream>>>(edata, rowptr, buf1, buf0, acc, ini, n_nodes);
    } else {
        int n4 = (n_nodes * D) / 4;
        float* cur = (float*)d_ws;
        float* nxt = cur + (size_t)n_nodes * D;
        lg_init_kernel<<<2048, 256, 0, stream>>>(ini, cur, acc, nxt, n4);
        int spmm_blocks = (E * 16 + 255) / 256;
        for (int layer = 0; layer < 3; ++layer) {
            lg_spmm_kernel<<<spmm_blocks, 256, 0, stream>>>(esrc, edst, ew, cur, nxt, E);
            lg_addzero_kernel<<<2048, 256, 0, stream>>>(acc, nxt, cur, n4);
            float* t = cur; cur = nxt; nxt = t;
        }
    }
}

// Round 4
// 692.599 us; speedup vs baseline: 17.5585x; 1.5756x over previous
//
#include <hip/hip_runtime.h>

// LightGCN forward: acc = sum over layers of (A^l @ X), A sparse COO (src,dst,w).
// Build dst-sorted CSR once per launch:
//   bhist/bscan  : global bucket (dst>>9) histogram + scan -> bucket bases
//   lg_part      : tiled partition; per-tile LDS hist + ONE global atomic per
//                  (tile,bucket) reserves a contiguous run -> single-CU line writes
//   lg_bfinal    : per-bucket (512-node) LDS counting sort -> dst-sorted edata + rowptr
// Then 3 atomic-free gather SpMM layers (wave/node, quarter-wave/edge, float4 lanes).

#define D 64
#define BSH 9
#define BW 512            // nodes per bucket = 1<<BSH
#define PTILE 16384       // edges per partition tile

__global__ void lg_zero_int(int* __restrict__ p, int n) {
    int i = blockIdx.x * blockDim.x + threadIdx.x;
    int st = gridDim.x * blockDim.x;
    for (; i < n; i += st) p[i] = 0;
}

// global bucket histogram, LDS-aggregated
__global__ void lg_bhist(const int* __restrict__ edst, int* __restrict__ bcount,
                         int E, int NB) {
    extern __shared__ int lcnt[];
    for (int i = threadIdx.x; i < NB; i += blockDim.x) lcnt[i] = 0;
    __syncthreads();
    int i = blockIdx.x * blockDim.x + threadIdx.x;
    int st = gridDim.x * blockDim.x;
    for (; i < E; i += st) atomicAdd(&lcnt[edst[i] >> BSH], 1);
    __syncthreads();
    for (int j = threadIdx.x; j < NB; j += blockDim.x) {
        int v = lcnt[j];
        if (v) atomicAdd(&bcount[j], v);
    }
}

// single-block scan over NB bucket counts; counts aliases bcur (pre-loaded).
__global__ __launch_bounds__(1024) void lg_bscan(const int* counts, int* bptr, int* bcur,
                                                 int NB, int E, int* rowptr, int n_nodes) {
    __shared__ int lds[1024];
    int tid = threadIdx.x;
    int per = (NB + 1023) >> 10;
    int lo = tid * per; if (lo > NB) lo = NB;
    int hi = lo + per;  if (hi > NB) hi = NB;
    int sum = 0;
    for (int i = lo; i < hi; ++i) sum += counts[i];
    lds[tid] = sum;
    __syncthreads();
    for (int off = 1; off < 1024; off <<= 1) {
        int v = (tid >= off) ? lds[tid - off] : 0;
        __syncthreads();
        lds[tid] += v;
        __syncthreads();
    }
    int run = lds[tid] - sum;
    for (int i = lo; i < hi; ++i) {
        int c = counts[i];          // load BEFORE overwriting (counts==bcur)
        bptr[i] = run;
        bcur[i] = run;
        run += c;
    }
    if (tid == 0) { bptr[NB] = E; rowptr[n_nodes] = E; }
}

// tiled partition: contiguous per-(tile,bucket) runs -> cache-local writes.
// record: {src | (dst&511)<<18, w_bits}; src<2^18 ok for n_nodes=150000.
__global__ __launch_bounds__(256) void lg_part(const int* __restrict__ esrc,
                                               const int* __restrict__ edst,
                                               const float* __restrict__ ew,
                                               int* __restrict__ bcur,
                                               int2* __restrict__ bbuf,
                                               int E, int NB) {
    extern __shared__ int sm[];          // cnt[NB] | base[NB]
    int* cnt = sm;
    int* base = sm + NB;
    int lo = blockIdx.x * PTILE;
    int hi = lo + PTILE; if (hi > E) hi = E;
    for (int i = threadIdx.x; i < NB; i += 256) cnt[i] = 0;
    __syncthreads();
    for (int i = lo + threadIdx.x; i < hi; i += 256)
        atomicAdd(&cnt[edst[i] >> BSH], 1);
    __syncthreads();
    for (int i = threadIdx.x; i < NB; i += 256) {
        int c = cnt[i];
        base[i] = c ? atomicAdd(&bcur[i], c) : 0;
        cnt[i] = 0;                       // reuse as run-local cursor
    }
    __syncthreads();
    for (int i = lo + threadIdx.x; i < hi; i += 256) {
        int d = edst[i];
        int b = d >> BSH;
        int p = base[b] + atomicAdd(&cnt[b], 1);
        bbuf[p] = make_int2(esrc[i] | ((d & (BW - 1)) << 18), __float_as_int(ew[i]));
    }
}

// per-bucket LDS counting sort (512 local nodes) -> dst-sorted edata + rowptr
__global__ __launch_bounds__(256) void lg_bfinal(const int2* __restrict__ bbuf,
                                                 const int* __restrict__ bptr,
                                                 int2* __restrict__ edata,
                                                 int* __restrict__ rowptr, int n_nodes) {
    __shared__ int cnt[BW];
    __shared__ int cur[BW];
    __shared__ int psum[256];
    int b = blockIdx.x;
    int s = bptr[b], e = bptr[b + 1];
    int tid = threadIdx.x;
    for (int i = tid; i < BW; i += 256) cnt[i] = 0;
    __syncthreads();
    for (int i = s + tid; i < e; i += 256)
        atomicAdd(&cnt[((unsigned)bbuf[i].x >> 18) & (BW - 1)], 1);
    __syncthreads();
    int c0 = cnt[2 * tid], c1 = cnt[2 * tid + 1];
    int mysum = c0 + c1;
    psum[tid] = mysum;
    __syncthreads();
    for (int off = 1; off < 256; off <<= 1) {
        int v = (tid >= off) ? psum[tid - off] : 0;
        __syncthreads();
        psum[tid] += v;
        __syncthreads();
    }
    int excl = psum[tid] - mysum;
    cur[2 * tid] = excl;
    cur[2 * tid + 1] = excl + c0;
    int node0 = b * BW + 2 * tid;
    if (node0 < n_nodes)     rowptr[node0]     = s + excl;
    if (node0 + 1 < n_nodes) rowptr[node0 + 1] = s + excl + c0;
    __syncthreads();
    for (int i = s + tid; i < e; i += 256) {
        int2 ed = bbuf[i];
        int loc = ((unsigned)ed.x >> 18) & (BW - 1);
        int p = s + atomicAdd(&cur[loc], 1);
        edata[p] = make_int2(ed.x & 0x3FFFF, ed.y);
    }
}

// gather SpMM: wave per dst node, quarter-wave per edge, float4 lanes, 16-edge unroll
template <bool FIRST, bool LAST>
__global__ __launch_bounds__(256) void lg_gather(const int2* __restrict__ edata,
                                                 const int* __restrict__ rowptr,
                                                 const float* __restrict__ x,
                                                 float* __restrict__ y,
                                                 float* __restrict__ acc,
                                                 const float* __restrict__ ini,
                                                 int n_nodes) {
    int wid = (blockIdx.x * blockDim.x + threadIdx.x) >> 6;
    int lane = threadIdx.x & 63;
    if (wid >= n_nodes) return;
    int q = lane >> 4, c = lane & 15;
    int start = rowptr[wid], end = rowptr[wid + 1];
    float ax = 0.f, ay = 0.f, az = 0.f, aw = 0.f;
    int base = start;
    for (; base + 16 <= end; base += 16) {
        int2 e0 = edata[base + q];
        int2 e1 = edata[base + 4 + q];
        int2 e2 = edata[base + 8 + q];
        int2 e3 = edata[base + 12 + q];
        float4 x0 = *((const float4*)(x + (size_t)e0.x * D) + c);
        float4 x1 = *((const float4*)(x + (size_t)e1.x * D) + c);
        float4 x2 = *((const float4*)(x + (size_t)e2.x * D) + c);
        float4 x3 = *((const float4*)(x + (size_t)e3.x * D) + c);
        float w0 = __int_as_float(e0.y), w1 = __int_as_float(e1.y);
        float w2 = __int_as_float(e2.y), w3 = __int_as_float(e3.y);
        ax += w0 * x0.x; ay += w0 * x0.y; az += w0 * x0.z; aw += w0 * x0.w;
        ax += w1 * x1.x; ay += w1 * x1.y; az += w1 * x1.z; aw += w1 * x1.w;
        ax += w2 * x2.x; ay += w2 * x2.y; az += w2 * x2.z; aw += w2 * x2.w;
        ax += w3 * x3.x; ay += w3 * x3.y; az += w3 * x3.z; aw += w3 * x3.w;
    }
    for (; base < end; base += 4) {
        int idx = base + q;
        if (idx < end) {
            int2 e0 = edata[idx];
            float w0 = __int_as_float(e0.y);
            float4 x0 = *((const float4*)(x + (size_t)e0.x * D) + c);
            ax += w0 * x0.x; ay += w0 * x0.y; az += w0 * x0.z; aw += w0 * x0.w;
        }
    }
    ax += __shfl_xor(ax, 16); ax += __shfl_xor(ax, 32);
    ay += __shfl_xor(ay, 16); ay += __shfl_xor(ay, 32);
    az += __shfl_xor(az, 16); az += __shfl_xor(az, 32);
    aw += __shfl_xor(aw, 16); aw += __shfl_xor(aw, 32);
    if (lane < 16) {
        size_t o = (size_t)wid * D + (size_t)c * 4;
        if (!LAST) *(float4*)(y + o) = make_float4(ax, ay, az, aw);
        if (FIRST) {
            float4 iv = *(const float4*)(ini + o);
            *(float4*)(acc + o) = make_float4(iv.x + ax, iv.y + ay, iv.z + az, iv.w + aw);
        } else {
            float4 av = *(float4*)(acc + o);
            *(float4*)(acc + o) = make_float4(av.x + ax, av.y + ay, av.z + az, av.w + aw);
        }
    }
}

// fallback (atomic scatter path, only if ws too small)
__global__ void lg_init_kernel(const float* __restrict__ ini, float* __restrict__ cur,
                               float* __restrict__ acc, float* __restrict__ nxt, int n4) {
    int i = blockIdx.x * blockDim.x + threadIdx.x;
    int stride = gridDim.x * blockDim.x;
    const float4* s = (const float4*)ini;
    float4* c = (float4*)cur; float4* a = (float4*)acc; float4* z = (float4*)nxt;
    float4 zero = make_float4(0.f, 0.f, 0.f, 0.f);
    for (; i < n4; i += stride) { float4 v = s[i]; c[i] = v; a[i] = v; z[i] = zero; }
}

__global__ void lg_spmm_kernel(const int* __restrict__ esrc, const int* __restrict__ edst,
                               const float* __restrict__ ew, const float* __restrict__ x,
                               float* __restrict__ y, int E) {
    int tid = blockIdx.x * blockDim.x + threadIdx.x;
    int e = tid >> 4;
    if (e >= E) return;
    int l = (tid & 15) << 2;
    int s = esrc[e]; int d = edst[e]; float w = ew[e];
    float4 v = *(const float4*)(x + s * D + l);
    float* yp = y + d * D + l;
    unsafeAtomicAdd(yp + 0, w * v.x);
    unsafeAtomicAdd(yp + 1, w * v.y);
    unsafeAtomicAdd(yp + 2, w * v.z);
    unsafeAtomicAdd(yp + 3, w * v.w);
}

__global__ void lg_addzero_kernel(float* __restrict__ acc, const float* __restrict__ nxt,
                                  float* __restrict__ zbuf, int n4) {
    int i = blockIdx.x * blockDim.x + threadIdx.x;
    int stride = gridDim.x * blockDim.x;
    float4* a = (float4*)acc; const float4* n = (const float4*)nxt; float4* z = (float4*)zbuf;
    float4 zero = make_float4(0.f, 0.f, 0.f, 0.f);
    for (; i < n4; i += stride) {
        float4 av = a[i]; float4 nv = n[i];
        av.x += nv.x; av.y += nv.y; av.z += nv.z; av.w += nv.w;
        a[i] = av; z[i] = zero;
    }
}

extern "C" void kernel_launch(void* const* d_in, const int* in_sizes, int n_in,
                              void* d_out, int out_size, void* d_ws, size_t ws_size,
                              hipStream_t stream) {
    const float* ini  = (const float*)d_in[0];
    const int*   esrc = (const int*)d_in[1];
    const int*   edst = (const int*)d_in[2];
    const float* ew   = (const float*)d_in[3];

    int n_nodes = in_sizes[0] / D;     // 150000
    int E       = in_sizes[1];         // 4.8M
    int NB      = (n_nodes + BW - 1) >> BSH;   // 293

    size_t embBytes   = (size_t)n_nodes * D * sizeof(float);   // 38.4 MB
    size_t edataBytes = (size_t)E * sizeof(int2);              // 38.4 MB
    size_t ptrBytes   = (((size_t)n_nodes + 1) * 4 + 15) & ~(size_t)15;
    size_t bptrBytes  = (((size_t)NB + 1) * 4 + 15) & ~(size_t)15;
    size_t need = 2 * embBytes + edataBytes + ptrBytes + bptrBytes + (size_t)NB * 4 + 64;

    float* acc = (float*)d_out;

    if (ws_size >= need) {
        char* p = (char*)d_ws;
        float* buf0   = (float*)p;  p += embBytes;
        float* buf1   = (float*)p;  p += embBytes;   // doubles as bbuf during build
        int2*  edata  = (int2*)p;   p += edataBytes;
        int*   rowptr = (int*)p;    p += ptrBytes;
        int*   bptr   = (int*)p;    p += bptrBytes;
        int*   bcur   = (int*)p;
        int2*  bbuf   = (int2*)buf1;

        int ntiles = (E + PTILE - 1) / PTILE;       // 293

        lg_zero_int<<<(NB + 255) / 256, 256, 0, stream>>>(bcur, NB);
        lg_bhist<<<256, 256, (size_t)NB * 4, stream>>>(edst, bcur, E, NB);
        lg_bscan<<<1, 1024, 0, stream>>>(bcur, bptr, bcur, NB, E, rowptr, n_nodes);
        lg_part<<<ntiles, 256, (size_t)NB * 8, stream>>>(esrc, edst, ew, bcur, bbuf, E, NB);
        lg_bfinal<<<NB, 256, 0, stream>>>(bbuf, bptr, edata, rowptr, n_nodes);

        int gblocks = (int)(((size_t)n_nodes * 64 + 255) / 256);
        lg_gather<true,  false><<<gblocks, 256, 0, stream>>>(edata, rowptr, ini,  buf0, acc, ini, n_nodes);
        lg_gather<false, false><<<gblocks, 256, 0, stream>>>(edata, rowptr, buf0, buf1, acc, ini, n_nodes);
        lg_gather<false, true ><<<gblocks, 256, 0, stream>>>(edata, rowptr, buf1, buf0, acc, ini, n_nodes);
    } else {
        int n4 = (n_nodes * D) / 4;
        float* cur = (float*)d_ws;
        float* nxt = cur + (size_t)n_nodes * D;
        lg_init_kernel<<<2048, 256, 0, stream>>>(ini, cur, acc, nxt, n4);
        int spmm_blocks = (E * 16 + 255) / 256;
        for (int layer = 0; layer < 3; ++layer) {
            lg_spmm_kernel<<<spmm_blocks, 256, 0, stream>>>(esrc, edst, ew, cur, nxt, E);
            lg_addzero_kernel<<<2048, 256, 0, stream>>>(acc, nxt, cur, n4);
            float* t = cur; cur = nxt; nxt = t;
        }
    }
}

// Round 5
// 487.671 us; speedup vs baseline: 24.9369x; 1.4202x over previous
//
#include <hip/hip_runtime.h>
#include <hip/hip_fp16.h>

// LightGCN forward: acc = sum over layers of (A^l @ X), A sparse COO (src,dst,w).
// Build dst-sorted CSR once per launch (bucket hist/scan -> tiled cache-local
// partition -> per-bucket LDS counting sort), then 3 atomic-free gather SpMM
// layers. Layer embeddings are staged in FP16 (halves gather bytes); the
// accumulator / output stays FP32.

#define D 64
#define BSH 9
#define BW 512            // nodes per bucket = 1<<BSH
#define PTILE 16384       // edges per partition tile

__global__ void lg_zero_int(int* __restrict__ p, int n) {
    int i = blockIdx.x * blockDim.x + threadIdx.x;
    int st = gridDim.x * blockDim.x;
    for (; i < n; i += st) p[i] = 0;
}

// fp32 -> fp16 conversion (4 floats / thread)
__global__ void lg_f2h(const float* __restrict__ in, __half* __restrict__ out, int n4) {
    int i = blockIdx.x * blockDim.x + threadIdx.x;
    int st = gridDim.x * blockDim.x;
    const float4* src = (const float4*)in;
    uint2* dst = (uint2*)out;
    for (; i < n4; i += st) {
        float4 v = src[i];
        __half2 a = __floats2half2_rn(v.x, v.y);
        __half2 b = __floats2half2_rn(v.z, v.w);
        uint2 u;
        u.x = *reinterpret_cast<unsigned int*>(&a);
        u.y = *reinterpret_cast<unsigned int*>(&b);
        dst[i] = u;
    }
}

// global bucket histogram, LDS-aggregated
__global__ void lg_bhist(const int* __restrict__ edst, int* __restrict__ bcount,
                         int E, int NB) {
    extern __shared__ int lcnt[];
    for (int i = threadIdx.x; i < NB; i += blockDim.x) lcnt[i] = 0;
    __syncthreads();
    int i = blockIdx.x * blockDim.x + threadIdx.x;
    int st = gridDim.x * blockDim.x;
    for (; i < E; i += st) atomicAdd(&lcnt[edst[i] >> BSH], 1);
    __syncthreads();
    for (int j = threadIdx.x; j < NB; j += blockDim.x) {
        int v = lcnt[j];
        if (v) atomicAdd(&bcount[j], v);
    }
}

// single-block scan over NB bucket counts; counts aliases bcur (pre-loaded).
__global__ __launch_bounds__(1024) void lg_bscan(const int* counts, int* bptr, int* bcur,
                                                 int NB, int E, int* rowptr, int n_nodes) {
    __shared__ int lds[1024];
    int tid = threadIdx.x;
    int per = (NB + 1023) >> 10;
    int lo = tid * per; if (lo > NB) lo = NB;
    int hi = lo + per;  if (hi > NB) hi = NB;
    int sum = 0;
    for (int i = lo; i < hi; ++i) sum += counts[i];
    lds[tid] = sum;
    __syncthreads();
    for (int off = 1; off < 1024; off <<= 1) {
        int v = (tid >= off) ? lds[tid - off] : 0;
        __syncthreads();
        lds[tid] += v;
        __syncthreads();
    }
    int run = lds[tid] - sum;
    for (int i = lo; i < hi; ++i) {
        int c = counts[i];          // load BEFORE overwriting (counts==bcur)
        bptr[i] = run;
        bcur[i] = run;
        run += c;
    }
    if (tid == 0) { bptr[NB] = E; rowptr[n_nodes] = E; }
}

// tiled partition: contiguous per-(tile,bucket) runs -> cache-local writes.
// record: {src | (dst&511)<<18, w_bits}; src<2^18 ok for n_nodes=150000.
__global__ __launch_bounds__(256) void lg_part(const int* __restrict__ esrc,
                                               const int* __restrict__ edst,
                                               const float* __restrict__ ew,
                                               int* __restrict__ bcur,
                                               int2* __restrict__ bbuf,
                                               int E, int NB) {
    extern __shared__ int sm[];          // cnt[NB] | base[NB]
    int* cnt = sm;
    int* base = sm + NB;
    int lo = blockIdx.x * PTILE;
    int hi = lo + PTILE; if (hi > E) hi = E;
    for (int i = threadIdx.x; i < NB; i += 256) cnt[i] = 0;
    __syncthreads();
    for (int i = lo + threadIdx.x; i < hi; i += 256)
        atomicAdd(&cnt[edst[i] >> BSH], 1);
    __syncthreads();
    for (int i = threadIdx.x; i < NB; i += 256) {
        int c = cnt[i];
        base[i] = c ? atomicAdd(&bcur[i], c) : 0;
        cnt[i] = 0;                       // reuse as run-local cursor
    }
    __syncthreads();
    for (int i = lo + threadIdx.x; i < hi; i += 256) {
        int d = edst[i];
        int b = d >> BSH;
        int p = base[b] + atomicAdd(&cnt[b], 1);
        bbuf[p] = make_int2(esrc[i] | ((d & (BW - 1)) << 18), __float_as_int(ew[i]));
    }
}

// per-bucket LDS counting sort (512 local nodes) -> dst-sorted edata + rowptr
__global__ __launch_bounds__(256) void lg_bfinal(const int2* __restrict__ bbuf,
                                                 const int* __restrict__ bptr,
                                                 int2* __restrict__ edata,
                                                 int* __restrict__ rowptr, int n_nodes) {
    __shared__ int cnt[BW];
    __shared__ int cur[BW];
    __shared__ int psum[256];
    int b = blockIdx.x;
    int s = bptr[b], e = bptr[b + 1];
    int tid = threadIdx.x;
    for (int i = tid; i < BW; i += 256) cnt[i] = 0;
    __syncthreads();
    for (int i = s + tid; i < e; i += 256)
        atomicAdd(&cnt[((unsigned)bbuf[i].x >> 18) & (BW - 1)], 1);
    __syncthreads();
    int c0 = cnt[2 * tid], c1 = cnt[2 * tid + 1];
    int mysum = c0 + c1;
    psum[tid] = mysum;
    __syncthreads();
    for (int off = 1; off < 256; off <<= 1) {
        int v = (tid >= off) ? psum[tid - off] : 0;
        __syncthreads();
        psum[tid] += v;
        __syncthreads();
    }
    int excl = psum[tid] - mysum;
    cur[2 * tid] = excl;
    cur[2 * tid + 1] = excl + c0;
    int node0 = b * BW + 2 * tid;
    if (node0 < n_nodes)     rowptr[node0]     = s + excl;
    if (node0 + 1 < n_nodes) rowptr[node0 + 1] = s + excl + c0;
    __syncthreads();
    for (int i = s + tid; i < e; i += 256) {
        int2 ed = bbuf[i];
        int loc = ((unsigned)ed.x >> 18) & (BW - 1);
        int p = s + atomicAdd(&cur[loc], 1);
        edata[p] = make_int2(ed.x & 0x3FFFF, ed.y);
    }
}

// gather SpMM (fp16 x): wave per dst node, quarter-wave per edge.
// lane = (q = edge slot 0..3, c = 8-byte chunk 0..15): each lane loads 4 halves.
template <bool FIRST, bool LAST>
__global__ __launch_bounds__(256) void lg_gather(const int2* __restrict__ edata,
                                                 const int* __restrict__ rowptr,
                                                 const __half* __restrict__ x,
                                                 __half* __restrict__ y,
                                                 float* __restrict__ acc,
                                                 const float* __restrict__ ini,
                                                 int n_nodes) {
    int wid = (blockIdx.x * blockDim.x + threadIdx.x) >> 6;
    int lane = threadIdx.x & 63;
    if (wid >= n_nodes) return;
    int q = lane >> 4, c = lane & 15;
    int start = rowptr[wid], end = rowptr[wid + 1];
    float ax = 0.f, ay = 0.f, az = 0.f, aw = 0.f;
    int base = start;
    for (; base + 16 <= end; base += 16) {
        int2 e0 = edata[base + q];
        int2 e1 = edata[base + 4 + q];
        int2 e2 = edata[base + 8 + q];
        int2 e3 = edata[base + 12 + q];
        uint2 u0 = *((const uint2*)(x + (size_t)e0.x * D) + c);
        uint2 u1 = *((const uint2*)(x + (size_t)e1.x * D) + c);
        uint2 u2 = *((const uint2*)(x + (size_t)e2.x * D) + c);
        uint2 u3 = *((const uint2*)(x + (size_t)e3.x * D) + c);
        float w0 = __int_as_float(e0.y), w1 = __int_as_float(e1.y);
        float w2 = __int_as_float(e2.y), w3 = __int_as_float(e3.y);
        {
            float2 f0 = __half22float2(*reinterpret_cast<__half2*>(&u0.x));
            float2 f1 = __half22float2(*reinterpret_cast<__half2*>(&u0.y));
            ax += w0 * f0.x; ay += w0 * f0.y; az += w0 * f1.x; aw += w0 * f1.y;
        }
        {
            float2 f0 = __half22float2(*reinterpret_cast<__half2*>(&u1.x));
            float2 f1 = __half22float2(*reinterpret_cast<__half2*>(&u1.y));
            ax += w1 * f0.x; ay += w1 * f0.y; az += w1 * f1.x; aw += w1 * f1.y;
        }
        {
            float2 f0 = __half22float2(*reinterpret_cast<__half2*>(&u2.x));
            float2 f1 = __half22float2(*reinterpret_cast<__half2*>(&u2.y));
            ax += w2 * f0.x; ay += w2 * f0.y; az += w2 * f1.x; aw += w2 * f1.y;
        }
        {
            float2 f0 = __half22float2(*reinterpret_cast<__half2*>(&u3.x));
            float2 f1 = __half22float2(*reinterpret_cast<__half2*>(&u3.y));
            ax += w3 * f0.x; ay += w3 * f0.y; az += w3 * f1.x; aw += w3 * f1.y;
        }
    }
    for (; base < end; base += 4) {
        int idx = base + q;
        if (idx < end) {
            int2 e0 = edata[idx];
            float w0 = __int_as_float(e0.y);
            uint2 u0 = *((const uint2*)(x + (size_t)e0.x * D) + c);
            float2 f0 = __half22float2(*reinterpret_cast<__half2*>(&u0.x));
            float2 f1 = __half22float2(*reinterpret_cast<__half2*>(&u0.y));
            ax += w0 * f0.x; ay += w0 * f0.y; az += w0 * f1.x; aw += w0 * f1.y;
        }
    }
    ax += __shfl_xor(ax, 16); ax += __shfl_xor(ax, 32);
    ay += __shfl_xor(ay, 16); ay += __shfl_xor(ay, 32);
    az += __shfl_xor(az, 16); az += __shfl_xor(az, 32);
    aw += __shfl_xor(aw, 16); aw += __shfl_xor(aw, 32);
    if (lane < 16) {
        size_t o = (size_t)wid * D + (size_t)c * 4;
        if (!LAST) {
            __half2 h0 = __floats2half2_rn(ax, ay);
            __half2 h1 = __floats2half2_rn(az, aw);
            uint2 u;
            u.x = *reinterpret_cast<unsigned int*>(&h0);
            u.y = *reinterpret_cast<unsigned int*>(&h1);
            *(uint2*)(y + o) = u;
        }
        if (FIRST) {
            float4 iv = *(const float4*)(ini + o);
            *(float4*)(acc + o) = make_float4(iv.x + ax, iv.y + ay, iv.z + az, iv.w + aw);
        } else {
            float4 av = *(float4*)(acc + o);
            *(float4*)(acc + o) = make_float4(av.x + ax, av.y + ay, av.z + az, av.w + aw);
        }
    }
}

// fallback (atomic scatter path, only if ws too small)
__global__ void lg_init_kernel(const float* __restrict__ ini, float* __restrict__ cur,
                               float* __restrict__ acc, float* __restrict__ nxt, int n4) {
    int i = blockIdx.x * blockDim.x + threadIdx.x;
    int stride = gridDim.x * blockDim.x;
    const float4* s = (const float4*)ini;
    float4* c = (float4*)cur; float4* a = (float4*)acc; float4* z = (float4*)nxt;
    float4 zero = make_float4(0.f, 0.f, 0.f, 0.f);
    for (; i < n4; i += stride) { float4 v = s[i]; c[i] = v; a[i] = v; z[i] = zero; }
}

__global__ void lg_spmm_kernel(const int* __restrict__ esrc, const int* __restrict__ edst,
                               const float* __restrict__ ew, const float* __restrict__ x,
                               float* __restrict__ y, int E) {
    int tid = blockIdx.x * blockDim.x + threadIdx.x;
    int e = tid >> 4;
    if (e >= E) return;
    int l = (tid & 15) << 2;
    int s = esrc[e]; int d = edst[e]; float w = ew[e];
    float4 v = *(const float4*)(x + s * D + l);
    float* yp = y + d * D + l;
    unsafeAtomicAdd(yp + 0, w * v.x);
    unsafeAtomicAdd(yp + 1, w * v.y);
    unsafeAtomicAdd(yp + 2, w * v.z);
    unsafeAtomicAdd(yp + 3, w * v.w);
}

__global__ void lg_addzero_kernel(float* __restrict__ acc, const float* __restrict__ nxt,
                                  float* __restrict__ zbuf, int n4) {
    int i = blockIdx.x * blockDim.x + threadIdx.x;
    int stride = gridDim.x * blockDim.x;
    float4* a = (float4*)acc; const float4* n = (const float4*)nxt; float4* z = (float4*)zbuf;
    float4 zero = make_float4(0.f, 0.f, 0.f, 0.f);
    for (; i < n4; i += stride) {
        float4 av = a[i]; float4 nv = n[i];
        av.x += nv.x; av.y += nv.y; av.z += nv.z; av.w += nv.w;
        a[i] = av; z[i] = zero;
    }
}

extern "C" void kernel_launch(void* const* d_in, const int* in_sizes, int n_in,
                              void* d_out, int out_size, void* d_ws, size_t ws_size,
                              hipStream_t stream) {
    const float* ini  = (const float*)d_in[0];
    const int*   esrc = (const int*)d_in[1];
    const int*   edst = (const int*)d_in[2];
    const float* ew   = (const float*)d_in[3];

    int n_nodes = in_sizes[0] / D;     // 150000
    int E       = in_sizes[1];         // 4.8M
    int NB      = (n_nodes + BW - 1) >> BSH;   // 293

    size_t hBytes     = ((size_t)n_nodes * D * sizeof(__half) + 255) & ~(size_t)255;  // 19.2 MB
    size_t edataBytes = (size_t)E * sizeof(int2);                                     // 38.4 MB
    size_t ptrBytes   = (((size_t)n_nodes + 1) * 4 + 15) & ~(size_t)15;
    size_t bptrBytes  = (((size_t)NB + 1) * 4 + 15) & ~(size_t)15;
    size_t need = 2 * hBytes + 2 * edataBytes + ptrBytes + bptrBytes + (size_t)NB * 4 + 64;

    float* acc = (float*)d_out;

    if (ws_size >= need) {
        char* p = (char*)d_ws;
        __half* h0    = (__half*)p; p += hBytes;
        __half* h1    = (__half*)p; p += hBytes;
        int2*  edata  = (int2*)p;   p += edataBytes;
        int2*  bbuf   = (int2*)p;   p += edataBytes;
        int*   rowptr = (int*)p;    p += ptrBytes;
        int*   bptr   = (int*)p;    p += bptrBytes;
        int*   bcur   = (int*)p;

        int ntiles = (E + PTILE - 1) / PTILE;       // 293
        int n4 = n_nodes * D / 4;

        lg_zero_int<<<(NB + 255) / 256, 256, 0, stream>>>(bcur, NB);
        lg_bhist<<<256, 256, (size_t)NB * 4, stream>>>(edst, bcur, E, NB);
        lg_bscan<<<1, 1024, 0, stream>>>(bcur, bptr, bcur, NB, E, rowptr, n_nodes);
        lg_part<<<ntiles, 256, (size_t)NB * 8, stream>>>(esrc, edst, ew, bcur, bbuf, E, NB);
        lg_f2h<<<2048, 256, 0, stream>>>(ini, h0, n4);
        lg_bfinal<<<NB, 256, 0, stream>>>(bbuf, bptr, edata, rowptr, n_nodes);

        int gblocks = (int)(((size_t)n_nodes * 64 + 255) / 256);
        lg_gather<true,  false><<<gblocks, 256, 0, stream>>>(edata, rowptr, h0, h1, acc, ini, n_nodes);
        lg_gather<false, false><<<gblocks, 256, 0, stream>>>(edata, rowptr, h1, h0, acc, ini, n_nodes);
        lg_gather<false, true ><<<gblocks, 256, 0, stream>>>(edata, rowptr, h0, h1, acc, ini, n_nodes);
    } else {
        int n4 = (n_nodes * D) / 4;
        float* cur = (float*)d_ws;
        float* nxt = cur + (size_t)n_nodes * D;
        lg_init_kernel<<<2048, 256, 0, stream>>>(ini, cur, acc, nxt, n4);
        int spmm_blocks = (E * 16 + 255) / 256;
        for (int layer = 0; layer < 3; ++layer) {
            lg_spmm_kernel<<<spmm_blocks, 256, 0, stream>>>(esrc, edst, ew, cur, nxt, E);
            lg_addzero_kernel<<<2048, 256, 0, stream>>>(acc, nxt, cur, n4);
            float* t = cur; cur = nxt; nxt = t;
        }
    }
}